// Round 1
// baseline (244.104 us; speedup 1.0000x reference)
//
#include <hip/hip_runtime.h>

#define N 8192
#define NCLS 81
#define PAD 300
#define NB 128  // u64 words per mask row (8192/64)

// ---------------- K1: decode + argmax pick + max score ----------------
__global__ __launch_bounds__(256) void decode_kernel(
    const float* __restrict__ meta, const float* __restrict__ deltas,
    const float* __restrict__ proposals, const float* __restrict__ scores,
    float4* __restrict__ sel, float* __restrict__ maxs) {
  int row = blockIdx.x * blockDim.x + threadIdx.x;
  if (row >= N) return;
  float H = meta[0], W = meta[1], sc = meta[2];
  const float* p = proposals + row * 4;
  float x1 = p[0] / sc, y1 = p[1] / sc, x2 = p[2] / sc, y2 = p[3] / sc;
  float w = x2 - x1 + 1.0f, h = y2 - y1 + 1.0f;
  float cx = x1 + 0.5f * w, cy = y1 + 0.5f * h;

  const float* s = scores + (size_t)row * NCLS;
  int best = 0;
  float bs = s[0];
  float ms = -1e30f;  // max over classes 1..80
  for (int c = 1; c < NCLS; ++c) {
    float v = s[c];
    if (v > bs) { bs = v; best = c; }   // strict > : first-max, matches jnp.argmax
    ms = fmaxf(ms, v);
  }

  const float* d = deltas + (size_t)row * (4 * NCLS) + best * 4;
  float pcx = d[0] * w + cx;
  float pcy = d[1] * h + cy;
  float pw = expf(d[2]) * w;
  float ph = expf(d[3]) * h;
  float lx = W - 1.0f, ly = H - 1.0f;
  float ox1 = fminf(fmaxf(pcx - 0.5f * pw, 0.0f), lx);
  float oy1 = fminf(fmaxf(pcy - 0.5f * ph, 0.0f), ly);
  float ox2 = fminf(fmaxf(pcx + 0.5f * pw, 0.0f), lx);
  float oy2 = fminf(fmaxf(pcy + 0.5f * ph, 0.0f), ly);
  sel[row] = make_float4(ox1, oy1, ox2, oy2);
  maxs[row] = ms;
}

// ---------------- K2: bitonic sort (score desc, idx asc) ----------------
__global__ __launch_bounds__(1024) void sort_kernel(
    const float* __restrict__ maxs, const float4* __restrict__ sel,
    unsigned long long* __restrict__ sortedKeys, float4* __restrict__ sortedBoxes) {
  __shared__ unsigned long long keys[N];
  int tid = threadIdx.x;
  for (int i = tid; i < N; i += 1024) {
    unsigned int sb = __float_as_uint(maxs[i]);  // scores in [0,1): positive, bits monotone
    keys[i] = ((unsigned long long)(~sb) << 32) | (unsigned int)i;
  }
  __syncthreads();
  for (int k = 2; k <= N; k <<= 1) {
    for (int j = k >> 1; j > 0; j >>= 1) {
      for (int t = tid; t < N / 2; t += 1024) {
        int i = ((t & ~(j - 1)) << 1) | (t & (j - 1));
        int p = i | j;
        bool up = ((i & k) == 0);
        unsigned long long a = keys[i], b = keys[p];
        if ((a > b) == up) { keys[i] = b; keys[p] = a; }
      }
      __syncthreads();
    }
  }
  for (int i = tid; i < N; i += 1024) {
    unsigned long long kk = keys[i];
    sortedKeys[i] = kk;
    sortedBoxes[i] = sel[(unsigned int)kk];
  }
}

// ---------------- K3: suppression bitmask build ----------------
// mask[i][cb] bit c set iff j = cb*64+c, j > i, IoU(i,j) > 0.5 (sorted order)
__global__ __launch_bounds__(64) void mask_kernel(
    const float4* __restrict__ boxes, unsigned long long* __restrict__ mask) {
  int rb = blockIdx.y, cb = blockIdx.x;
  int r = rb * 64 + threadIdx.x;
  if (cb < rb) {  // lower triangle: must still zero-fill (ws is poisoned)
    mask[(size_t)r * NB + cb] = 0ull;
    return;
  }
  __shared__ float4 cbox[64];
  cbox[threadIdx.x] = boxes[cb * 64 + threadIdx.x];
  __syncthreads();
  float4 bi = boxes[r];
  float areaA = fmaxf(bi.z - bi.x, 0.0f) * fmaxf(bi.w - bi.y, 0.0f);
  unsigned long long bits = 0ull;
#pragma unroll 8
  for (int c = 0; c < 64; ++c) {
    int j = cb * 64 + c;
    float4 bj = cbox[c];
    float areaB = fmaxf(bj.z - bj.x, 0.0f) * fmaxf(bj.w - bj.y, 0.0f);
    float lxv = fmaxf(bi.x, bj.x), lyv = fmaxf(bi.y, bj.y);
    float rxv = fminf(bi.z, bj.z), ryv = fminf(bi.w, bj.w);
    float iw = fmaxf(rxv - lxv, 0.0f), ih = fmaxf(ryv - lyv, 0.0f);
    float inter = iw * ih;
    float iou = inter / (areaA + areaB - inter + 1e-8f);
    if (j > r && iou > 0.5f) bits |= (1ull << c);
  }
  mask[(size_t)r * NB + cb] = bits;
}

// ---------------- K4: serial greedy scan (1 wave) ----------------
__global__ __launch_bounds__(64) void nms_scan_kernel(
    const unsigned long long* __restrict__ mask, int* __restrict__ kept,
    int* __restrict__ num_kept) {
  int lane = threadIdx.x;  // 64 lanes; lane owns remv words 2*lane, 2*lane+1
  unsigned long long r0 = 0ull, r1 = 0ull;
  int cnt = 0;
  for (int i = 0; i < N; ++i) {
    int w = i >> 6;
    unsigned long long v = __shfl((w & 1) ? r1 : r0, w >> 1);
    if (!((v >> (i & 63)) & 1ull)) {
      if (lane == 0) kept[cnt] = i;
      cnt++;
      if (cnt >= PAD) break;  // nothing after the 300th keep can matter
      const unsigned long long* row = mask + (size_t)i * NB;
      // coalesced 1KB row read: 16B per lane
      ulonglong2 m2 = ((const ulonglong2*)row)[lane];
      r0 |= m2.x;
      r1 |= m2.y;
    }
  }
  if (lane == 0) *num_kept = cnt;
}

// ---------------- K5: gather outputs ----------------
__global__ __launch_bounds__(128) void gather_kernel(
    const int* __restrict__ kept, const int* __restrict__ num_kept_p,
    const unsigned long long* __restrict__ sortedKeys,
    const float4* __restrict__ sortedBoxes, const float* __restrict__ scores,
    float* __restrict__ out) {
  int r = blockIdx.x;  // 0..299
  int t = threadIdx.x;
  float* boxes_out = out;             // (300,4)
  float* scores_out = out + PAD * 4;  // (300,81)
  int nk = *num_kept_p;
  bool valid = r < nk;
  int pos = valid ? kept[r] : 0;
  if (t < NCLS) {
    unsigned int orig = (unsigned int)sortedKeys[pos];
    scores_out[(size_t)r * NCLS + t] = valid ? scores[(size_t)orig * NCLS + t] : 0.0f;
  }
  if (t == 96) {
    float4 b = sortedBoxes[pos];
    if (!valid) b = make_float4(0.f, 0.f, 0.f, 0.f);
    ((float4*)boxes_out)[r] = b;
  }
}

extern "C" void kernel_launch(void* const* d_in, const int* in_sizes, int n_in,
                              void* d_out, int out_size, void* d_ws, size_t ws_size,
                              hipStream_t stream) {
  const float* meta = (const float*)d_in[0];
  const float* deltas = (const float*)d_in[1];
  const float* proposals = (const float*)d_in[2];
  const float* scores = (const float*)d_in[3];
  float* out = (float*)d_out;
  char* ws = (char*)d_ws;

  // workspace layout
  float4* sel = (float4*)(ws + 0);                                // 131072 B
  float* maxs = (float*)(ws + 131072);                            // 32768 B
  unsigned long long* sortedKeys = (unsigned long long*)(ws + 163840);  // 65536 B
  float4* sortedBoxes = (float4*)(ws + 229376);                   // 131072 B
  int* kept = (int*)(ws + 360448);                                // 1200 B
  int* num_kept = (int*)(ws + 362496);                            // 4 B
  unsigned long long* mask = (unsigned long long*)(ws + 393216);  // 8 MiB

  decode_kernel<<<N / 256, 256, 0, stream>>>(meta, deltas, proposals, scores, sel, maxs);
  sort_kernel<<<1, 1024, 0, stream>>>(maxs, sel, sortedKeys, sortedBoxes);
  mask_kernel<<<dim3(NB, NB), 64, 0, stream>>>(sortedBoxes, mask);
  nms_scan_kernel<<<1, 64, 0, stream>>>(mask, kept, num_kept);
  gather_kernel<<<PAD, 128, 0, stream>>>(kept, num_kept, sortedKeys, sortedBoxes, scores, out);
}

// Round 2
// 202.375 us; speedup vs baseline: 1.2062x; 1.2062x over previous
//
#include <hip/hip_runtime.h>

#define N 8192
#define NCLS 81
#define PAD 300
#define NPANEL 16      // panels of 512 columns
#define PANW 512       // columns per panel
#define PANW64 8       // u64 words per panel segment (512/64)

// ---------------- K1: decode + argmax pick + max score ----------------
__global__ __launch_bounds__(256) void decode_kernel(
    const float* __restrict__ meta, const float* __restrict__ deltas,
    const float* __restrict__ proposals, const float* __restrict__ scores,
    float4* __restrict__ sel, float* __restrict__ maxs) {
  int row = blockIdx.x * blockDim.x + threadIdx.x;
  if (row >= N) return;
  float H = meta[0], W = meta[1], sc = meta[2];
  const float* p = proposals + row * 4;
  float x1 = p[0] / sc, y1 = p[1] / sc, x2 = p[2] / sc, y2 = p[3] / sc;
  float w = x2 - x1 + 1.0f, h = y2 - y1 + 1.0f;
  float cx = x1 + 0.5f * w, cy = y1 + 0.5f * h;

  const float* s = scores + (size_t)row * NCLS;
  int best = 0;
  float bs = s[0];
  float ms = -1e30f;  // max over classes 1..80
  for (int c = 1; c < NCLS; ++c) {
    float v = s[c];
    if (v > bs) { bs = v; best = c; }   // strict > : first-max, matches jnp.argmax
    ms = fmaxf(ms, v);
  }

  const float* d = deltas + (size_t)row * (4 * NCLS) + best * 4;
  float pcx = d[0] * w + cx;
  float pcy = d[1] * h + cy;
  float pw = expf(d[2]) * w;
  float ph = expf(d[3]) * h;
  float lx = W - 1.0f, ly = H - 1.0f;
  float ox1 = fminf(fmaxf(pcx - 0.5f * pw, 0.0f), lx);
  float oy1 = fminf(fmaxf(pcy - 0.5f * ph, 0.0f), ly);
  float ox2 = fminf(fmaxf(pcx + 0.5f * pw, 0.0f), lx);
  float oy2 = fminf(fmaxf(pcy + 0.5f * ph, 0.0f), ly);
  sel[row] = make_float4(ox1, oy1, ox2, oy2);
  maxs[row] = ms;
}

// ---------------- K2: bitonic sort (score desc, idx asc) ----------------
__global__ __launch_bounds__(1024) void sort_kernel(
    const float* __restrict__ maxs, const float4* __restrict__ sel,
    unsigned long long* __restrict__ sortedKeys, float4* __restrict__ sortedBoxes) {
  __shared__ unsigned long long keys[N];
  int tid = threadIdx.x;
  for (int i = tid; i < N; i += 1024) {
    unsigned int sb = __float_as_uint(maxs[i]);  // scores in [0,1): positive, bits monotone
    keys[i] = ((unsigned long long)(~sb) << 32) | (unsigned int)i;
  }
  __syncthreads();
  for (int k = 2; k <= N; k <<= 1) {
    for (int j = k >> 1; j > 0; j >>= 1) {
      for (int t = tid; t < N / 2; t += 1024) {
        int i = ((t & ~(j - 1)) << 1) | (t & (j - 1));
        int p = i | j;
        bool up = ((i & k) == 0);
        unsigned long long a = keys[i], b = keys[p];
        if ((a > b) == up) { keys[i] = b; keys[p] = a; }
      }
      __syncthreads();
    }
  }
  for (int i = tid; i < N; i += 1024) {
    unsigned long long kk = keys[i];
    sortedKeys[i] = kk;
    sortedBoxes[i] = sel[(unsigned int)kk];
  }
}

// ---------------- K3: suppression bitmask build (panel-major layout) ----------------
// word for (row r, col-block cb) stored at mask[((cb>>3)*N + r)*8 + (cb&7)]
// bit c set iff j = cb*64+c, j > r, IoU(r,j) > 0.5 (sorted order)
__global__ __launch_bounds__(64) void mask_kernel(
    const float4* __restrict__ boxes, unsigned long long* __restrict__ mask) {
  int rb = blockIdx.y, cb = blockIdx.x;
  int r = rb * 64 + threadIdx.x;
  size_t dst = ((size_t)(cb >> 3) * N + r) * PANW64 + (cb & 7);
  if (cb < rb) {  // lower triangle: zero-fill (ws is poisoned; slab reads rely on 0)
    mask[dst] = 0ull;
    return;
  }
  __shared__ float4 cbox[64];
  cbox[threadIdx.x] = boxes[cb * 64 + threadIdx.x];
  __syncthreads();
  float4 bi = boxes[r];
  float areaA = fmaxf(bi.z - bi.x, 0.0f) * fmaxf(bi.w - bi.y, 0.0f);
  unsigned long long bits = 0ull;
#pragma unroll 8
  for (int c = 0; c < 64; ++c) {
    int j = cb * 64 + c;
    float4 bj = cbox[c];
    float areaB = fmaxf(bj.z - bj.x, 0.0f) * fmaxf(bj.w - bj.y, 0.0f);
    float lxv = fmaxf(bi.x, bj.x), lyv = fmaxf(bi.y, bj.y);
    float rxv = fminf(bi.z, bj.z), ryv = fminf(bi.w, bj.w);
    float iw = fmaxf(rxv - lxv, 0.0f), ih = fmaxf(ryv - lyv, 0.0f);
    float inter = iw * ih;
    float iou = inter / (areaA + areaB - inter + 1e-8f);
    if (j > r && iou > 0.5f) bits |= (1ull << c);
  }
  mask[dst] = bits;
}

// ---------------- K4: serial greedy scan, panel-blocked, LDS-resident ----------------
__global__ __launch_bounds__(64) void nms_scan_kernel(
    const unsigned long long* __restrict__ maskP, int* __restrict__ kept,
    int* __restrict__ num_kept) {
  __shared__ unsigned long long slab[PANW * PANW64];  // 32 KiB diagonal slab
  __shared__ int keptIdx[PAD];
  int lane = threadIdx.x;
  int w8 = lane & 7;  // this lane mirrors panel-remv word w8
  int cnt = 0;

  for (int p = 0; p < NPANEL && cnt < PAD; ++p) {
    int base = p * PANW;
    const unsigned long long* pbase = maskP + (size_t)p * N * PANW64;
    __syncthreads();  // keptIdx writes (lane 0) visible before batch-OR

    // batch-OR: panel-p segments of all keeps so far (independent loads, one latency)
    unsigned long long acc = 0ull;
    for (int t0 = 0; t0 < cnt; t0 += 8) {
      int t = t0 + (lane >> 3);
      if (t < cnt) acc |= pbase[(size_t)keptIdx[t] * PANW64 + w8];
    }
    acc |= __shfl_xor(acc, 8);
    acc |= __shfl_xor(acc, 16);
    acc |= __shfl_xor(acc, 32);
    unsigned long long remv = acc;  // every lane holds word (lane&7)

    // copy diagonal slab (rows [base, base+512) x this panel) into LDS: 32 KiB
    {
      const ulonglong2* src = (const ulonglong2*)(pbase + (size_t)base * PANW64);
      ulonglong2* dst = (ulonglong2*)slab;
#pragma unroll
      for (int it = 0; it < (PANW * PANW64 / 2) / 64; ++it)
        dst[it * 64 + lane] = src[it * 64 + lane];
    }
    __syncthreads();

    // serial in-panel scan
    int li = 0;
    while (li < PANW && cnt < PAD) {
      int w = li >> 6;
      unsigned long long v = __shfl(remv, w) >> (li & 63);
      unsigned long long inv = ~v;
      if (inv == 0ull) { li = (w + 1) << 6; continue; }
      int off = __ffsll((unsigned long long)inv) - 1;
      if ((li & 63) + off >= 64) { li = (w + 1) << 6; continue; }
      li += off;
      // li is kept
      int gi = base + li;
      if (lane == 0) { kept[cnt] = gi; keptIdx[cnt] = gi; }
      cnt++;
      if (cnt >= PAD) break;
      remv |= slab[li * PANW64 + w8];  // ds_read_b64, ~120cy — the dependent hop
      li += 1;
    }
  }
  if (lane == 0) *num_kept = cnt;
}

// ---------------- K5: gather outputs ----------------
__global__ __launch_bounds__(128) void gather_kernel(
    const int* __restrict__ kept, const int* __restrict__ num_kept_p,
    const unsigned long long* __restrict__ sortedKeys,
    const float4* __restrict__ sortedBoxes, const float* __restrict__ scores,
    float* __restrict__ out) {
  int r = blockIdx.x;  // 0..299
  int t = threadIdx.x;
  float* boxes_out = out;             // (300,4)
  float* scores_out = out + PAD * 4;  // (300,81)
  int nk = *num_kept_p;
  bool valid = r < nk;
  int pos = valid ? kept[r] : 0;
  if (t < NCLS) {
    unsigned int orig = (unsigned int)sortedKeys[pos];
    scores_out[(size_t)r * NCLS + t] = valid ? scores[(size_t)orig * NCLS + t] : 0.0f;
  }
  if (t == 96) {
    float4 b = sortedBoxes[pos];
    if (!valid) b = make_float4(0.f, 0.f, 0.f, 0.f);
    ((float4*)boxes_out)[r] = b;
  }
}

extern "C" void kernel_launch(void* const* d_in, const int* in_sizes, int n_in,
                              void* d_out, int out_size, void* d_ws, size_t ws_size,
                              hipStream_t stream) {
  const float* meta = (const float*)d_in[0];
  const float* deltas = (const float*)d_in[1];
  const float* proposals = (const float*)d_in[2];
  const float* scores = (const float*)d_in[3];
  float* out = (float*)d_out;
  char* ws = (char*)d_ws;

  // workspace layout
  float4* sel = (float4*)(ws + 0);                                      // 131072 B
  float* maxs = (float*)(ws + 131072);                                  // 32768 B
  unsigned long long* sortedKeys = (unsigned long long*)(ws + 163840);  // 65536 B
  float4* sortedBoxes = (float4*)(ws + 229376);                         // 131072 B
  int* kept = (int*)(ws + 360448);                                      // 1200 B
  int* num_kept = (int*)(ws + 362496);                                  // 4 B
  unsigned long long* mask = (unsigned long long*)(ws + 393216);        // 8 MiB panel-major

  decode_kernel<<<N / 256, 256, 0, stream>>>(meta, deltas, proposals, scores, sel, maxs);
  sort_kernel<<<1, 1024, 0, stream>>>(maxs, sel, sortedKeys, sortedBoxes);
  mask_kernel<<<dim3(N / 64, N / 64), 64, 0, stream>>>(sortedBoxes, mask);
  nms_scan_kernel<<<1, 64, 0, stream>>>(mask, kept, num_kept);
  gather_kernel<<<PAD, 128, 0, stream>>>(kept, num_kept, sortedKeys, sortedBoxes, scores, out);
}

// Round 3
// 166.260 us; speedup vs baseline: 1.4682x; 1.2172x over previous
//
#include <hip/hip_runtime.h>

#define N 8192
#define NCLS 81
#define PAD 300
#define NPANEL 16      // panels of 512 columns
#define PANW 512       // columns per panel
#define PANW64 8       // u64 words per panel segment (512/64)
#define JSPLIT 8       // rank kernel j-dimension split

// ---------------- K1: decode + argmax pick + key pack + rank zero ----------------
__global__ __launch_bounds__(256) void decode_kernel(
    const float* __restrict__ meta, const float* __restrict__ deltas,
    const float* __restrict__ proposals, const float* __restrict__ scores,
    float4* __restrict__ sel, unsigned long long* __restrict__ keys,
    int* __restrict__ rank) {
  int row = blockIdx.x * blockDim.x + threadIdx.x;
  if (row >= N) return;
  float H = meta[0], W = meta[1], sc = meta[2];
  const float* p = proposals + row * 4;
  float x1 = p[0] / sc, y1 = p[1] / sc, x2 = p[2] / sc, y2 = p[3] / sc;
  float w = x2 - x1 + 1.0f, h = y2 - y1 + 1.0f;
  float cx = x1 + 0.5f * w, cy = y1 + 0.5f * h;

  const float* s = scores + (size_t)row * NCLS;
  int best = 0;
  float bs = s[0];
  float ms = -1e30f;  // max over classes 1..80
  for (int c = 1; c < NCLS; ++c) {
    float v = s[c];
    if (v > bs) { bs = v; best = c; }   // strict > : first-max, matches jnp.argmax
    ms = fmaxf(ms, v);
  }

  const float* d = deltas + (size_t)row * (4 * NCLS) + best * 4;
  float pcx = d[0] * w + cx;
  float pcy = d[1] * h + cy;
  float pw = expf(d[2]) * w;
  float ph = expf(d[3]) * h;
  float lx = W - 1.0f, ly = H - 1.0f;
  float ox1 = fminf(fmaxf(pcx - 0.5f * pw, 0.0f), lx);
  float oy1 = fminf(fmaxf(pcy - 0.5f * ph, 0.0f), ly);
  float ox2 = fminf(fmaxf(pcx + 0.5f * pw, 0.0f), lx);
  float oy2 = fminf(fmaxf(pcy + 0.5f * ph, 0.0f), ly);
  sel[row] = make_float4(ox1, oy1, ox2, oy2);
  // sort key: (score desc, idx asc) == ascending u64 of (~score_bits)<<32 | idx
  keys[row] = ((unsigned long long)(~__float_as_uint(ms)) << 32) | (unsigned int)row;
  rank[row] = 0;
}

// ---------------- K2a: brute-force rank (stable sort of unique keys) ----------------
__global__ __launch_bounds__(256) void rank_kernel(
    const unsigned long long* __restrict__ keys, int* __restrict__ rank) {
  int i = blockIdx.x * 256 + threadIdx.x;
  unsigned long long ki = keys[i];
  int j0 = blockIdx.y * (N / JSPLIT);
  int c = 0;
#pragma unroll 8
  for (int j = j0; j < j0 + N / JSPLIT; ++j) {
    c += (keys[j] < ki);  // keys[j] wave-uniform -> scalarized
  }
  atomicAdd(&rank[i], c);
}

// ---------------- K2b: scatter into sorted order ----------------
__global__ __launch_bounds__(256) void scatter_kernel(
    const int* __restrict__ rank, const float4* __restrict__ sel,
    int* __restrict__ sortedIdx, float4* __restrict__ sortedBoxes) {
  int i = blockIdx.x * 256 + threadIdx.x;
  int r = rank[i];          // exact permutation (keys unique)
  sortedIdx[r] = i;         // keys[i] low 32 bits == i
  sortedBoxes[r] = sel[i];
}

// ---------------- K3: suppression bitmask build (panel-major layout) ----------------
// word for (row r, col-block cb) stored at mask[((cb>>3)*N + r)*8 + (cb&7)]
// bit c set iff j = cb*64+c, j > r, IoU(r,j) > 0.5 (sorted order)
__global__ __launch_bounds__(64) void mask_kernel(
    const float4* __restrict__ boxes, unsigned long long* __restrict__ mask) {
  int rb = blockIdx.y, cb = blockIdx.x;
  int r = rb * 64 + threadIdx.x;
  size_t dst = ((size_t)(cb >> 3) * N + r) * PANW64 + (cb & 7);
  if (cb < rb) {  // lower triangle: zero-fill (ws is poisoned; slab reads rely on 0)
    mask[dst] = 0ull;
    return;
  }
  __shared__ float4 cbox[64];
  cbox[threadIdx.x] = boxes[cb * 64 + threadIdx.x];
  __syncthreads();
  float4 bi = boxes[r];
  float areaA = fmaxf(bi.z - bi.x, 0.0f) * fmaxf(bi.w - bi.y, 0.0f);
  unsigned long long bits = 0ull;
#pragma unroll 8
  for (int c = 0; c < 64; ++c) {
    int j = cb * 64 + c;
    float4 bj = cbox[c];
    float areaB = fmaxf(bj.z - bj.x, 0.0f) * fmaxf(bj.w - bj.y, 0.0f);
    float lxv = fmaxf(bi.x, bj.x), lyv = fmaxf(bi.y, bj.y);
    float rxv = fminf(bi.z, bj.z), ryv = fminf(bi.w, bj.w);
    float iw = fmaxf(rxv - lxv, 0.0f), ih = fmaxf(ryv - lyv, 0.0f);
    float inter = iw * ih;
    float iou = inter / (areaA + areaB - inter + 1e-8f);
    if (j > r && iou > 0.5f) bits |= (1ull << c);
  }
  mask[dst] = bits;
}

// ---------------- K4: serial greedy scan, panel-blocked, LDS-resident ----------------
__global__ __launch_bounds__(64) void nms_scan_kernel(
    const unsigned long long* __restrict__ maskP, int* __restrict__ kept,
    int* __restrict__ num_kept) {
  __shared__ unsigned long long slab[PANW * PANW64];  // 32 KiB diagonal slab
  __shared__ int keptIdx[PAD];
  int lane = threadIdx.x;
  int w8 = lane & 7;  // this lane mirrors panel-remv word w8
  int cnt = 0;

  for (int p = 0; p < NPANEL && cnt < PAD; ++p) {
    int base = p * PANW;
    const unsigned long long* pbase = maskP + (size_t)p * N * PANW64;
    __syncthreads();  // keptIdx writes (lane 0) visible before batch-OR

    // batch-OR: panel-p segments of all keeps so far (independent loads, one latency)
    unsigned long long acc = 0ull;
    for (int t0 = 0; t0 < cnt; t0 += 8) {
      int t = t0 + (lane >> 3);
      if (t < cnt) acc |= pbase[(size_t)keptIdx[t] * PANW64 + w8];
    }
    acc |= __shfl_xor(acc, 8);
    acc |= __shfl_xor(acc, 16);
    acc |= __shfl_xor(acc, 32);
    unsigned long long remv = acc;  // every lane holds word (lane&7)

    // copy diagonal slab (rows [base, base+512) x this panel) into LDS: 32 KiB
    {
      const ulonglong2* src = (const ulonglong2*)(pbase + (size_t)base * PANW64);
      ulonglong2* dst = (ulonglong2*)slab;
#pragma unroll
      for (int it = 0; it < (PANW * PANW64 / 2) / 64; ++it)
        dst[it * 64 + lane] = src[it * 64 + lane];
    }
    __syncthreads();

    // serial in-panel scan
    int li = 0;
    while (li < PANW && cnt < PAD) {
      int w = li >> 6;
      unsigned long long v = __shfl(remv, w) >> (li & 63);
      unsigned long long inv = ~v;
      if (inv == 0ull) { li = (w + 1) << 6; continue; }
      int off = __ffsll((unsigned long long)inv) - 1;
      if ((li & 63) + off >= 64) { li = (w + 1) << 6; continue; }
      li += off;
      // li is kept
      int gi = base + li;
      if (lane == 0) { kept[cnt] = gi; keptIdx[cnt] = gi; }
      cnt++;
      if (cnt >= PAD) break;
      remv |= slab[li * PANW64 + w8];  // ds_read_b64, ~120cy — the dependent hop
      li += 1;
    }
  }
  if (lane == 0) *num_kept = cnt;
}

// ---------------- K5: gather outputs ----------------
__global__ __launch_bounds__(128) void gather_kernel(
    const int* __restrict__ kept, const int* __restrict__ num_kept_p,
    const int* __restrict__ sortedIdx, const float4* __restrict__ sortedBoxes,
    const float* __restrict__ scores, float* __restrict__ out) {
  int r = blockIdx.x;  // 0..299
  int t = threadIdx.x;
  float* boxes_out = out;             // (300,4)
  float* scores_out = out + PAD * 4;  // (300,81)
  int nk = *num_kept_p;
  bool valid = r < nk;
  int pos = valid ? kept[r] : 0;
  if (t < NCLS) {
    int orig = sortedIdx[pos];
    scores_out[(size_t)r * NCLS + t] = valid ? scores[(size_t)orig * NCLS + t] : 0.0f;
  }
  if (t == 96) {
    float4 b = sortedBoxes[pos];
    if (!valid) b = make_float4(0.f, 0.f, 0.f, 0.f);
    ((float4*)boxes_out)[r] = b;
  }
}

extern "C" void kernel_launch(void* const* d_in, const int* in_sizes, int n_in,
                              void* d_out, int out_size, void* d_ws, size_t ws_size,
                              hipStream_t stream) {
  const float* meta = (const float*)d_in[0];
  const float* deltas = (const float*)d_in[1];
  const float* proposals = (const float*)d_in[2];
  const float* scores = (const float*)d_in[3];
  float* out = (float*)d_out;
  char* ws = (char*)d_ws;

  // workspace layout
  float4* sel = (float4*)(ws + 0);                                      // 131072 B
  unsigned long long* keys = (unsigned long long*)(ws + 131072);        // 65536 B
  int* rank = (int*)(ws + 196608);                                      // 32768 B
  int* sortedIdx = (int*)(ws + 229376);                                 // 32768 B
  float4* sortedBoxes = (float4*)(ws + 262144);                         // 131072 B
  int* kept = (int*)(ws + 393216);                                      // 1200 B
  int* num_kept = (int*)(ws + 395264);                                  // 4 B
  unsigned long long* mask = (unsigned long long*)(ws + 409600);        // 8 MiB panel-major

  decode_kernel<<<N / 256, 256, 0, stream>>>(meta, deltas, proposals, scores, sel, keys, rank);
  rank_kernel<<<dim3(N / 256, JSPLIT), 256, 0, stream>>>(keys, rank);
  scatter_kernel<<<N / 256, 256, 0, stream>>>(rank, sel, sortedIdx, sortedBoxes);
  mask_kernel<<<dim3(N / 64, N / 64), 64, 0, stream>>>(sortedBoxes, mask);
  nms_scan_kernel<<<1, 64, 0, stream>>>(mask, kept, num_kept);
  gather_kernel<<<PAD, 128, 0, stream>>>(kept, num_kept, sortedIdx, sortedBoxes, scores, out);
}